// Round 3
// baseline (32404.279 us; speedup 1.0000x reference)
//
#include <hip/hip_runtime.h>
#include <hip/hip_fp16.h>
#include <cmath>

// Problem constants (reference: B=256, T=512, IN=64, R=2048)
constexpr int kB  = 256;
constexpr int kT  = 512;
constexpr int kIN = 64;
constexpr int kR  = 2048;

constexpr int kBlocks = 256;   // 64 n-bands x 4 m-bands -> 1 block/CU, all resident
constexpr int BN = 32;         // n per block (W-band rows, held in registers)
constexpr int BM = 64;         // batches per block
constexpr int CH  = 256;       // k per staged s-chunk
constexpr int NCH = kR / CH;   // 8 chunks
constexpr int XST = 72;        // xs LDS row stride (halfs), 16B-aligned rows
constexpr int SST = CH + 8;    // ss LDS row stride (halfs) = 264 -> balanced banks

typedef _Float16 f16x8 __attribute__((ext_vector_type(8)));
typedef float    f32x4 __attribute__((ext_vector_type(4)));
typedef unsigned long long u64;

#define MFMA16(a, b, c) __builtin_amdgcn_mfma_f32_16x16x32_f16((a), (b), (c), 0, 0, 0)

__device__ __forceinline__ f16x8 cvt8(float4 a, float4 b) {
    f16x8 v;
    v[0] = (_Float16)a.x; v[1] = (_Float16)a.y; v[2] = (_Float16)a.z; v[3] = (_Float16)a.w;
    v[4] = (_Float16)b.x; v[5] = (_Float16)b.y; v[6] = (_Float16)b.z; v[7] = (_Float16)b.w;
    return v;
}

// 16-half (32 B) coherent granule: 4 x u64 agent-scope atomic loads (cross-XCD
// safe), stored to LDS as 2 x 16B writes (row stride 528 B keeps 16B align).
struct G16 { u64 a, b, c, d; };

__device__ __forceinline__ G16 load16(const _Float16* p) {
    const u64* q = (const u64*)p;
    G16 g;
    g.a = __hip_atomic_load(q + 0, __ATOMIC_RELAXED, __HIP_MEMORY_SCOPE_AGENT);
    g.b = __hip_atomic_load(q + 1, __ATOMIC_RELAXED, __HIP_MEMORY_SCOPE_AGENT);
    g.c = __hip_atomic_load(q + 2, __ATOMIC_RELAXED, __HIP_MEMORY_SCOPE_AGENT);
    g.d = __hip_atomic_load(q + 3, __ATOMIC_RELAXED, __HIP_MEMORY_SCOPE_AGENT);
    return g;
}
__device__ __forceinline__ void store16(_Float16* p, G16 g) {
    u64* q = (u64*)p;
    q[0] = g.a; q[1] = g.b; q[2] = g.c; q[3] = g.d;
}

// Persistent ESN kernel: all 512 steps in one launch.
// Block = 64 batches x 32 reservoir-units, W-band resident in VGPRs (loaded
// from HBM exactly once). Waves: (mh in {0,1}) x (q in {0..3}) = m-half x
// k-phase; 4-way k-partials reduced through LDS each step, fused tanh, state
// exchanged via AGENT-scope atomics + device counter barrier.
__global__ __launch_bounds__(512, 2) void esn_persist(
    const float* __restrict__ X,     // [B, T, IN]
    const float* __restrict__ Win,   // [R, IN]
    const float* __restrict__ W,     // [R, R]
    float* __restrict__ out,         // [B, R]
    _Float16* __restrict__ sbuf0,
    _Float16* __restrict__ sbuf1,
    unsigned int* __restrict__ ctr)
{
    __shared__ __align__(16) _Float16 xs[64 * XST];   // 9216 B
    __shared__ __align__(16) _Float16 ss[64 * SST];   // 33792 B (aliased as fp32 partials)

    const int tid  = threadIdx.x;
    const int wave = tid >> 6, lane = tid & 63;
    const int quad = lane >> 4, l16 = lane & 15;
    const int mh = wave >> 2;        // m-half: rows [mh*32, mh*32+32)
    const int q  = wave & 3;         // k-phase: kk ≡ q (mod 4)
    const int n0 = (blockIdx.x & 63) * BN;
    const int m0 = (blockIdx.x >> 6) * BM;

    // ---- one-time: W-band -> register B-frags (f16) ----
    // wfrag[h][2c+half] = W[n0+h*16+l16][kk*32 + quad*8 + j], kk = 8c + 4*half + q
    f16x8 wfrag[2][2 * NCH];
    #pragma unroll
    for (int h = 0; h < 2; ++h) {
        const float* wrow = W + (size_t)(n0 + h * 16 + l16) * kR;
        #pragma unroll
        for (int kki = 0; kki < 2 * NCH; ++kki) {
            const int kk = (kki >> 1) * 8 + (kki & 1) * 4 + q;
            const float* p = wrow + kk * 32 + quad * 8;
            wfrag[h][kki] = cvt8(*(const float4*)p, *(const float4*)(p + 4));
        }
    }
    f16x8 winfrag[2] = {};
    if (q < 2) {
        #pragma unroll
        for (int h = 0; h < 2; ++h) {
            const float* p = Win + (size_t)(n0 + h * 16 + l16) * kIN + q * 32 + quad * 8;
            winfrag[h] = cvt8(*(const float4*)p, *(const float4*)(p + 4));
        }
    }

    // staging geometry
    const int xrow = tid >> 3, xc8 = (tid & 7) * 8;   // X: 8 floats -> 8 halfs/thread
    const int srow = tid >> 4;                        // 0..31 (granule rows srow, srow+32)
    const int scol = (tid & 15) * 16;                 // 16 halfs (32 B) per granule

    #pragma unroll 1
    for (int t = 0; t < kT; ++t) {
        f32x4 acc[2][2] = {};

        // ---- stage X_t -> xs (f16) ----
        {
            const float* xp = X + ((size_t)(m0 + xrow) * kT + t) * kIN + xc8;
            *(f16x8*)&xs[xrow * XST + xc8] = cvt8(*(const float4*)xp, *(const float4*)(xp + 4));
        }
        __syncthreads();

        // ---- input term (depends only on X; issues before barrier wait) ----
        if (q < 2) {
            #pragma unroll
            for (int i = 0; i < 2; ++i) {
                f16x8 a = *(const f16x8*)&xs[((2 * mh + i) * 16 + l16) * XST + q * 32 + quad * 8];
                acc[i][0] = MFMA16(a, winfrag[0], acc[i][0]);
                acc[i][1] = MFMA16(a, winfrag[1], acc[i][1]);
            }
        }

        // ---- recurrent term: K-loop over s_{t-1} ----
        if (t > 0) {
            const _Float16* sprev = (t & 1) ? sbuf0 : sbuf1;
            if (tid == 0) {
                const unsigned int need = (unsigned int)kBlocks * (unsigned int)t;
                while (__hip_atomic_load(ctr, __ATOMIC_ACQUIRE, __HIP_MEMORY_SCOPE_AGENT) < need)
                    __builtin_amdgcn_s_sleep(2);
            }
            __syncthreads();

            // preload chunk 0 (full 64 x 256 halfs: 512 threads x 2 granules)
            {
                G16 g0 = load16(sprev + (size_t)(m0 + srow) * kR + scol);
                G16 g1 = load16(sprev + (size_t)(m0 + srow + 32) * kR + scol);
                store16(&ss[srow * SST + scol], g0);
                store16(&ss[(srow + 32) * SST + scol], g1);
            }
            __syncthreads();

            #pragma unroll
            for (int c = 0; c < NCH; ++c) {
                G16 p0, p1;
                if (c + 1 < NCH) {  // prefetch next chunk while computing this one
                    p0 = load16(sprev + (size_t)(m0 + srow) * kR + (c + 1) * CH + scol);
                    p1 = load16(sprev + (size_t)(m0 + srow + 32) * kR + (c + 1) * CH + scol);
                }
                #pragma unroll
                for (int half = 0; half < 2; ++half) {
                    const int kloc = q * 32 + half * 128 + quad * 8;
                    f16x8 av0 = *(const f16x8*)&ss[((2 * mh + 0) * 16 + l16) * SST + kloc];
                    f16x8 av1 = *(const f16x8*)&ss[((2 * mh + 1) * 16 + l16) * SST + kloc];
                    acc[0][0] = MFMA16(av0, wfrag[0][2 * c + half], acc[0][0]);
                    acc[0][1] = MFMA16(av0, wfrag[1][2 * c + half], acc[0][1]);
                    acc[1][0] = MFMA16(av1, wfrag[0][2 * c + half], acc[1][0]);
                    acc[1][1] = MFMA16(av1, wfrag[1][2 * c + half], acc[1][1]);
                }
                __syncthreads();   // everyone done reading ss chunk c
                if (c + 1 < NCH) {
                    store16(&ss[srow * SST + scol], p0);
                    store16(&ss[(srow + 32) * SST + scol], p1);
                    __syncthreads();
                }
            }
        }

        // ---- reduce 4 k-phase partials through LDS, tanh, store ----
        float* pf = (float*)ss;  // 4 x [64 x 32] fp32 = 32 KB, reuses ss
        #pragma unroll
        for (int i = 0; i < 2; ++i)
            #pragma unroll
            for (int h = 0; h < 2; ++h)
                #pragma unroll
                for (int r = 0; r < 4; ++r)
                    pf[q * 2048 + (mh * 32 + i * 16 + quad * 4 + r) * 32 + h * 16 + l16] = acc[i][h][r];
        __syncthreads();

        const int idx = tid * 4, ml = idx >> 5, nl = idx & 31;
        f32x4 v0 = *(const f32x4*)&pf[0 * 2048 + idx];
        f32x4 v1 = *(const f32x4*)&pf[1 * 2048 + idx];
        f32x4 v2 = *(const f32x4*)&pf[2 * 2048 + idx];
        f32x4 v3 = *(const f32x4*)&pf[3 * 2048 + idx];
        float o0 = tanhf(v0[0] + v1[0] + v2[0] + v3[0]);
        float o1 = tanhf(v0[1] + v1[1] + v2[1] + v3[1]);
        float o2 = tanhf(v0[2] + v1[2] + v2[2] + v3[2]);
        float o3 = tanhf(v0[3] + v1[3] + v2[3] + v3[3]);

        if (t < kT - 1) {
            _Float16* sout = (t & 1) ? sbuf1 : sbuf0;
            union { u64 u; _Float16 h[4]; } pk;
            pk.h[0] = (_Float16)o0; pk.h[1] = (_Float16)o1;
            pk.h[2] = (_Float16)o2; pk.h[3] = (_Float16)o3;
            __hip_atomic_store((u64*)(sout + (size_t)(m0 + ml) * kR + n0 + nl), pk.u,
                               __ATOMIC_RELAXED, __HIP_MEMORY_SCOPE_AGENT);
            __threadfence();
            __syncthreads();   // all stores done; also fences LDS reuse for next step
            if (tid == 0)
                __hip_atomic_fetch_add(ctr, 1u, __ATOMIC_RELEASE, __HIP_MEMORY_SCOPE_AGENT);
        } else {
            float4 o; o.x = o0; o.y = o1; o.z = o2; o.w = o3;
            *(float4*)(out + (size_t)(m0 + ml) * kR + n0 + nl) = o;
        }
    }
}

extern "C" void kernel_launch(void* const* d_in, const int* in_sizes, int n_in,
                              void* d_out, int out_size, void* d_ws, size_t ws_size,
                              hipStream_t stream)
{
    const float* X   = (const float*)d_in[0];  // [B, T, IN]
    const float* Win = (const float*)d_in[1];  // [R, IN]
    const float* W   = (const float*)d_in[2];  // [R, R]
    float* out = (float*)d_out;                // [B, R]

    char* ws = (char*)d_ws;
    _Float16* s0 = (_Float16*)ws;                                  // 1 MB
    _Float16* s1 = (_Float16*)(ws + (size_t)kB * kR * 2);          // 1 MB
    unsigned int* ctr = (unsigned int*)(ws + 2 * (size_t)kB * kR * 2);

    hipMemsetAsync(ctr, 0, sizeof(unsigned int), stream);
    esn_persist<<<kBlocks, 512, 0, stream>>>(X, Win, W, out, s0, s1, ctr);
}